// Round 7
// baseline (212.322 us; speedup 1.0000x reference)
//
#include <hip/hip_runtime.h>
#include <hip/hip_bf16.h>

// Fused: QKV proj (+bias) -> RoPE(Q,K) -> MHA softmax -> out proj (+bias)
// B=8 S=1024 D=1024 H=16 Dk=64.
// GEMM engine (R7): BM=128 x BN=128, BK=32, 4 waves (2Mx2N, 64x64/wave),
// 3-slot LDS rotation (48KB -> 3 blocks/CU), stage j+2 during tile j,
// vmcnt(4) counted waits, lane-linear subtiled LDS (0 conflicts).
// Rationale: per-block gload_lds staging caps at ~20-26 GB/s regardless of
// schedule (R2/R4/R6 all 22.7% MfmaUtil at 1 block/CU); m103's 37% came from
// 3 blocks/CU x 18 GB/s. Scale staging via TLP, not pipeline depth.

typedef __bf16 bf16_t;
typedef __bf16 bf16x8 __attribute__((ext_vector_type(8)));
typedef float  f32x4  __attribute__((ext_vector_type(4)));

static __device__ __forceinline__ f32x4 mfma16(bf16x8 a, bf16x8 b, f32x4 c) {
  return __builtin_amdgcn_mfma_f32_16x16x32_bf16(a, b, c, 0, 0, 0);
}
static __device__ __forceinline__ void gload_lds16(const void* g, void* l) {
  __builtin_amdgcn_global_load_lds((const __attribute__((address_space(1))) void*)g,
                                   (__attribute__((address_space(3))) void*)l,
                                   16, 0, 0);
}
#define VMCNT(n) asm volatile("s_waitcnt vmcnt(" #n ")" ::: "memory")
#define VMCNT0() asm volatile("s_waitcnt vmcnt(0)" ::: "memory")
#define LGKM0()  do { asm volatile("s_waitcnt lgkmcnt(0)" ::: "memory"); \
                      __builtin_amdgcn_sched_barrier(0); } while (0)
#define SBAR() do { __builtin_amdgcn_sched_barrier(0); __builtin_amdgcn_s_barrier(); \
                    __builtin_amdgcn_sched_barrier(0); } while (0)

#if __has_builtin(__builtin_amdgcn_exp2f)
#define EXP2F(x) __builtin_amdgcn_exp2f(x)
#else
#define EXP2F(x) exp2f(x)
#endif

// ---------------- prep kernels ----------------
__global__ void k_cast(const float* __restrict__ s, bf16_t* __restrict__ d, int n4) {
  int i = blockIdx.x * 256 + threadIdx.x;
  if (i >= n4) return;
  float4 v = reinterpret_cast<const float4*>(s)[i];
  union { bf16_t b[4]; unsigned long long u; } pk;
  pk.b[0] = (bf16_t)v.x; pk.b[1] = (bf16_t)v.y;
  pk.b[2] = (bf16_t)v.z; pk.b[3] = (bf16_t)v.w;
  reinterpret_cast<unsigned long long*>(d)[i] = pk.u;
}

__global__ void k_cast_w(const float* __restrict__ w0, const float* __restrict__ w1,
                         const float* __restrict__ w2, const float* __restrict__ w3,
                         bf16_t* __restrict__ dst) {
  int z = blockIdx.y;
  const float* s = (z == 0) ? w0 : (z == 1) ? w1 : (z == 2) ? w2 : w3;
  int i = blockIdx.x * 256 + threadIdx.x;
  float4 v = reinterpret_cast<const float4*>(s)[i];
  union { bf16_t b[4]; unsigned long long u; } pk;
  pk.b[0] = (bf16_t)v.x; pk.b[1] = (bf16_t)v.y;
  pk.b[2] = (bf16_t)v.z; pk.b[3] = (bf16_t)v.w;
  reinterpret_cast<unsigned long long*>(dst + (size_t)z * 1048576)[i] = pk.u;
}

__global__ void k_rope_table(const int* __restrict__ pos, float2* __restrict__ rt) {
  int s = blockIdx.x * 8 + (threadIdx.x >> 5);
  int f = threadIdx.x & 31;
  float p = (float)pos[s];
  float inv = powf(10000.0f, -(float)(2 * f) / 64.0f);
  float a = p * inv;
  rt[s * 32 + f] = make_float2(cosf(a), sinf(a));
}

// ======= 128x128 GEMM body: BK=32, 32 K-tiles, 3 LDS slots (48KB) =======
// Slot (16384B): A 8KB [group g(8) x 1KB], B 8KB at +8192.
//   1KB group = 16 rows x 32 k, lane-ordered: lane (hi*16+c) holds
//   row c, k in [hi*8, hi*8+8) -> frag read = base + lane*16 (0-conflict).
// Stage: 4 loads/thread; granule s_ = l*256+t -> row ((s_>>6)<<4)|(s_&15),
//   koff ((s_>>4)&3)*8; LDS dst linear t*16 (permutation folded into source).
// Pipeline: stage(j+2) during tile j; vmcnt(4) end-of-tile -> tile j+1
//   resident at its phase start (each wave waits its own 4, barrier makes it
//   block-wide). Slot (j+2)%3 = (j-1)%3: reads drained per-wave (LGKM0)
//   before phase j-1's trailing barrier -> no WAR race.
#define GEMM128_BODY(Aptr, Bptr)                                               \
  __shared__ alignas(16) char LDSbuf[49152];                                   \
  const int t = threadIdx.x;                                                   \
  const int lane = t & 63, w = t >> 6;                                         \
  const int hi = lane >> 4, c = lane & 15;                                     \
  const int wm2 = w >> 1, wn2 = w & 1;                                         \
  const bf16_t* gA[2]; const bf16_t* gB[2];                                    \
  _Pragma("unroll") for (int l = 0; l < 2; ++l) {                              \
    int s_ = l * 256 + t;                                                      \
    int row = ((s_ >> 6) << 4) | (s_ & 15);                                    \
    int koff = ((s_ >> 4) & 3) * 8;                                            \
    gA[l] = (Aptr) + (size_t)(i0 + row) * 1024 + koff;                         \
    gB[l] = (Bptr) + (size_t)(e0 + row) * 1024 + koff;                         \
  }                                                                            \
  auto stage = [&](int slot, int kt) {                                         \
    char* d0 = LDSbuf + slot * 16384 + t * 16;                                 \
    gload_lds16(gA[0] + kt * 32, d0);                                          \
    gload_lds16(gA[1] + kt * 32, d0 + 4096);                                   \
    gload_lds16(gB[0] + kt * 32, d0 + 8192);                                   \
    gload_lds16(gB[1] + kt * 32, d0 + 12288);                                  \
  };                                                                           \
  f32x4 acc[4][4] = {};                                                        \
  stage(0, 0); stage(1, 1);                                                    \
  VMCNT(4);                                                                    \
  SBAR();                                                                      \
  const char* laB = LDSbuf + wm2 * 4096 + lane * 16;                           \
  const char* lbB = LDSbuf + 8192 + wn2 * 4096 + lane * 16;                    \
  int sl = 0, sls = 2;                                                         \
  for (int j = 0; j < 32; ++j) {                                               \
    const char* la = laB + sl * 16384;                                         \
    const char* lb = lbB + sl * 16384;                                         \
    bf16x8 af[4], bg[4];                                                       \
    _Pragma("unroll") for (int fr = 0; fr < 4; ++fr)                           \
      af[fr] = *(const bf16x8*)(la + fr * 1024);                               \
    _Pragma("unroll") for (int nc = 0; nc < 4; ++nc)                           \
      bg[nc] = *(const bf16x8*)(lb + nc * 1024);                               \
    if (j < 30) stage(sls, j + 2);                                             \
    SBAR();                                                                    \
    LGKM0();                                                                   \
    __builtin_amdgcn_s_setprio(1);                                             \
    _Pragma("unroll") for (int fr = 0; fr < 4; ++fr)                           \
      _Pragma("unroll") for (int nc = 0; nc < 4; ++nc)                         \
        acc[fr][nc] = mfma16(af[fr], bg[nc], acc[fr][nc]);                     \
    __builtin_amdgcn_s_setprio(0);                                             \
    if (j < 30) { VMCNT(4); } else if (j == 30) { VMCNT0(); }                  \
    SBAR();                                                                    \
    sl = (sl == 2) ? 0 : sl + 1;                                               \
    sls = (sls == 2) ? 0 : sls + 1;                                            \
  }

// ---------------- fused QKV GEMM: N=3072 (Wq|Wk|Wv concat) ----------------
// 1536 blocks = 64 m x 24 n (n fastest, no XCD swizzle), 2 rounds at 3/CU.
__global__ __launch_bounds__(256, 3) void k_gemm_qkv(
    const bf16_t* __restrict__ Xb, const bf16_t* __restrict__ Wqkv,
    const float* __restrict__ bq, const float* __restrict__ bk,
    const float* __restrict__ bv, const float2* __restrict__ rt,
    bf16_t* __restrict__ Qh, bf16_t* __restrict__ Kh, bf16_t* __restrict__ Vt) {
  const int bid = blockIdx.x;
  const int i0 = (bid / 24) * 128;
  const int e0 = (bid % 24) * 128;

  GEMM128_BODY(Xb, Wqkv)

  // Epilogue: one head per wave (64-col window at ez0).
  const int z = e0 >> 10;                       // 0:Q 1:K 2:V
  const int ez0 = (e0 & 1023) + wn2 * 64;       // multiple of 64
  const int h = ez0 >> 6;
  const float* bias = (z == 0) ? bq : (z == 1) ? bk : bv;
  if (z == 2) {
#pragma unroll
    for (int fr = 0; fr < 4; ++fr) {
      int i = i0 + wm2 * 64 + fr * 16 + hi * 4;
      int b_ = i >> 10, s = i & 1023;
#pragma unroll
      for (int nc = 0; nc < 4; ++nc) {
        int dk = nc * 16 + c;
        float bv_ = bias[ez0 + dk];
        union { bf16_t b[4]; unsigned long long u; } pk;
#pragma unroll
        for (int r = 0; r < 4; ++r) pk.b[r] = (bf16_t)(acc[fr][nc][r] + bv_);
        __builtin_memcpy(&Vt[((size_t)((b_ * 16 + h) * 64 + dk)) * 1024 + s], pk.b, 8);
      }
    }
  } else {
    bf16_t* O = (z == 0) ? Qh : Kh;
    // Q folds 1/sqrt(64) * log2(e): attn softmax runs in exp2 domain.
    const float scl = (z == 0) ? 0.18033688011112042f : 1.0f;
#pragma unroll
    for (int fr = 0; fr < 4; ++fr) {
      int i = i0 + wm2 * 64 + fr * 16 + hi * 4;
      int b_ = i >> 10, sbase = i & 1023;
      size_t obase = (size_t)((b_ * 16 + h) * 1024);
#pragma unroll
      for (int nc = 0; nc < 2; ++nc) {          // f<32; partner f+32 = frag nc+2
        int f = nc * 16 + c;
        float b1_ = bias[ez0 + f], b2_ = bias[ez0 + f + 32];
#pragma unroll
        for (int r = 0; r < 4; ++r) {
          int s = sbase + r;
          float2 cs = rt[s * 32 + f];
          float q1 = acc[fr][nc][r] + b1_;
          float q2 = acc[fr][nc + 2][r] + b2_;
          O[(obase + s) * 64 + f] = (bf16_t)((q1 * cs.x - q2 * cs.y) * scl);
          O[(obase + s) * 64 + f + 32] = (bf16_t)((q1 * cs.y + q2 * cs.x) * scl);
        }
      }
    }
  }
}

// ---------------- out projection (same engine): 512 blocks = 64m x 8n ------
__global__ __launch_bounds__(256, 3) void k_gemm_out(
    const bf16_t* __restrict__ Og, const bf16_t* __restrict__ Wob,
    const float* __restrict__ bo, float* __restrict__ out) {
  const int bid = blockIdx.x;
  const int i0 = (bid >> 3) * 128;
  const int e0 = (bid & 7) * 128;

  GEMM128_BODY(Og, Wob)

#pragma unroll
  for (int fr = 0; fr < 4; ++fr) {
    int i = i0 + wm2 * 64 + fr * 16 + hi * 4;
#pragma unroll
    for (int nc = 0; nc < 4; ++nc) {
      int e = e0 + wn2 * 64 + nc * 16 + c;
      float bv_ = bo[e];
#pragma unroll
      for (int r = 0; r < 4; ++r)
        out[(size_t)(i + r) * 1024 + e] = acc[fr][nc][r] + bv_;
    }
  }
}

// ---------------- flash attention (R5, verified) ----------------
__global__ __launch_bounds__(512) void k_attn(
    const bf16_t* __restrict__ Qh, const bf16_t* __restrict__ Kh,
    const bf16_t* __restrict__ Vt, bf16_t* __restrict__ Og) {
  __shared__ alignas(16) char KL[3][8192];
  __shared__ alignas(16) char VL[3][8192];
  __shared__ alignas(16) char PL[8][2048];
  const int t = threadIdx.x;
  const int lane = t & 63, w = t >> 6;
  const int hi = lane >> 4, c = lane & 15;
  const int bid = blockIdx.x;
  const int wg = (bid & 7) * 128 + (bid >> 3);
  const int bh = wg >> 3, qt = wg & 7;
  const size_t base = (size_t)bh * 64 * 1024;
  const int q0 = qt * 128 + w * 16;

  const int sc = t & 15, sks = (t >> 4) & 7, sfr = t >> 7;
  const bf16_t* srcK = Kh + base + (size_t)(sfr * 16 + sc) * 64 + sks * 8;
  const bf16_t* srcV = Vt + base + (size_t)(sfr * 16 + sc) * 1024 + sks * 8;
  auto stage = [&](int b3, int kt) {
    gload_lds16(srcK + (size_t)kt * 64 * 64, &KL[b3][0] + t * 16);
    gload_lds16(srcV + kt * 64, &VL[b3][0] + t * 16);
  };

  bf16x8 qf[2];
  qf[0] = *(const bf16x8*)&Qh[base + (size_t)(q0 + c) * 64 + hi * 8];
  qf[1] = *(const bf16x8*)&Qh[base + (size_t)(q0 + c) * 64 + 32 + hi * 8];

  f32x4 o[4] = {};
  float m = -1e30f, lsum = 0.f;

  stage(0, 0);
  stage(1, 1);
  VMCNT(2);
  SBAR();

  char* const plw = &PL[w][0];
  for (int kt = 0; kt < 16; ++kt) {
    const int b3 = kt % 3;
    if (kt + 2 < 16) stage((kt + 2) % 3, kt + 2);

    const char* kb = &KL[b3][0] + lane * 16;
    f32x4 st[4] = {};
#pragma unroll
    for (int ni = 0; ni < 4; ++ni)
#pragma unroll
      for (int kk = 0; kk < 2; ++kk)
        st[ni] = mfma16(*(const bf16x8*)(kb + ni * 2048 + kk * 1024), qf[kk], st[ni]);

    float pmax = -1e30f;
#pragma unroll
    for (int ni = 0; ni < 4; ++ni)
#pragma unroll
      for (int r = 0; r < 4; ++r) pmax = fmaxf(pmax, st[ni][r]);
    pmax = fmaxf(pmax, __shfl_xor(pmax, 16));
    pmax = fmaxf(pmax, __shfl_xor(pmax, 32));
    float mn = fmaxf(m, pmax);
    float scale = EXP2F(m - mn);
    m = mn;
    float psum = 0.f;
#pragma unroll
    for (int ni = 0; ni < 4; ++ni) {
      union { bf16_t b[4]; unsigned long long u; } pk;
#pragma unroll
      for (int r = 0; r < 4; ++r) {
        float p = EXP2F(st[ni][r] - mn);
        psum += p;
        pk.b[r] = (bf16_t)p;
      }
      __builtin_memcpy(plw + (ni * 2 + (hi >> 1)) * 256 + c * 16 + (hi & 1) * 8,
                       pk.b, 8);
    }
    psum += __shfl_xor(psum, 16);
    psum += __shfl_xor(psum, 32);
    lsum = lsum * scale + psum;
#pragma unroll
    for (int od = 0; od < 4; ++od)
#pragma unroll
      for (int r = 0; r < 4; ++r) o[od][r] *= scale;

    const char* vb = &VL[b3][0] + lane * 16;
#pragma unroll
    for (int od = 0; od < 4; ++od)
#pragma unroll
      for (int kk = 0; kk < 2; ++kk) {
        bf16x8 vf = *(const bf16x8*)(vb + od * 2048 + kk * 1024);
        bf16x8 pa = *(const bf16x8*)(plw + kk * 1024 + lane * 16);
        o[od] = mfma16(vf, pa, o[od]);
      }

    if (kt < 14) { VMCNT(2); } else if (kt == 14) { VMCNT0(); }
    if (kt < 15) SBAR();
  }

  float invl = 1.0f / lsum;
  int b_ = bh >> 4, h = bh & 15;
  size_t rowoff = ((size_t)(b_ * 1024 + q0 + c)) * 1024 + h * 64;
#pragma unroll
  for (int od = 0; od < 4; ++od) {
    union { bf16_t b[4]; unsigned long long u; } pk;
#pragma unroll
    for (int r = 0; r < 4; ++r) pk.b[r] = (bf16_t)(o[od][r] * invl);
    __builtin_memcpy(&Og[rowoff + od * 16 + hi * 4], pk.b, 8);
  }
}

extern "C" void kernel_launch(void* const* d_in, const int* in_sizes, int n_in,
                              void* d_out, int out_size, void* d_ws, size_t ws_size,
                              hipStream_t stream) {
  const float* x = (const float*)d_in[0];
  const int* pos = (const int*)d_in[1];
  const float* Wq = (const float*)d_in[2];
  const float* bq = (const float*)d_in[3];
  const float* Wk = (const float*)d_in[4];
  const float* bk = (const float*)d_in[5];
  const float* Wv = (const float*)d_in[6];
  const float* bv = (const float*)d_in[7];
  const float* Wo = (const float*)d_in[8];
  const float* bo = (const float*)d_in[9];
  float* out = (float*)d_out;

  // ws: [0,16M) Xb (reused as Og) | [16M,24M) Wqkv(6M)+Wob(2M) contiguous
  //     [24M,40M) Vt | [42M,..) rope table.  Q,K live in d_out (32MB).
  char* ws = (char*)d_ws;
  bf16_t* Xb = (bf16_t*)ws;
  bf16_t* Wqkv = (bf16_t*)(ws + (16u << 20));
  bf16_t* Wob = (bf16_t*)(ws + (22u << 20));
  bf16_t* Vt = (bf16_t*)(ws + (24u << 20));
  float2* rt = (float2*)(ws + (42u << 20));
  bf16_t* Qh = (bf16_t*)d_out;
  bf16_t* Kh = (bf16_t*)d_out + (size_t)8 * 1024 * 1024;
  bf16_t* Og = Xb;

  k_cast<<<8192, 256, 0, stream>>>(x, Xb, 8192 * 1024 / 4);
  k_cast_w<<<dim3(1024, 4), 256, 0, stream>>>(Wq, Wk, Wv, Wo, Wqkv);
  k_rope_table<<<128, 256, 0, stream>>>(pos, rt);

  k_gemm_qkv<<<1536, 256, 0, stream>>>(Xb, Wqkv, bq, bk, bv, rt, Qh, Kh, Vt);
  k_attn<<<1024, 512, 0, stream>>>(Qh, Kh, Vt, Og);
  k_gemm_out<<<512, 256, 0, stream>>>(Og, Wob, bo, out);
}

// Round 8
// 184.859 us; speedup vs baseline: 1.1486x; 1.1486x over previous
//
#include <hip/hip_runtime.h>
#include <hip/hip_bf16.h>

// Fused: QKV proj (+bias) -> RoPE(Q,K) -> MHA softmax -> out proj (+bias)
// B=8 S=1024 D=1024 H=16 Dk=64.
// GEMM engine (R8): BM=256 x BN=128, BK=32, 8 waves (4Mx2N, 64x64/wave),
// 3-slot LDS rotation (72KB -> 2 blocks/CU), stage j+2 during iter j,
// counted VMCNT(3) (never 0 mid-loop), ONE raw s_barrier per iter,
// COMPILER-SCHEDULED interior (no sched_barrier / lgkm-drain / setprio):
// R2..R7 all pinned at ~2.2 TF/CU because the rigid lockstep serialized the
// LDS-read window against the MFMA window; m97's 3.56 TF/CU comes from the
// compiler's fine-grained lgkmcnt interleave, which this restores.

typedef __bf16 bf16_t;
typedef __bf16 bf16x8 __attribute__((ext_vector_type(8)));
typedef float  f32x4  __attribute__((ext_vector_type(4)));

static __device__ __forceinline__ f32x4 mfma16(bf16x8 a, bf16x8 b, f32x4 c) {
  return __builtin_amdgcn_mfma_f32_16x16x32_bf16(a, b, c, 0, 0, 0);
}
static __device__ __forceinline__ void gload_lds16(const void* g, void* l) {
  __builtin_amdgcn_global_load_lds((const __attribute__((address_space(1))) void*)g,
                                   (__attribute__((address_space(3))) void*)l,
                                   16, 0, 0);
}
#define VMCNT(n) asm volatile("s_waitcnt vmcnt(" #n ")" ::: "memory")
#define VMCNT0() asm volatile("s_waitcnt vmcnt(0)" ::: "memory")
#define BAR() __builtin_amdgcn_s_barrier()

#if __has_builtin(__builtin_amdgcn_exp2f)
#define EXP2F(x) __builtin_amdgcn_exp2f(x)
#else
#define EXP2F(x) exp2f(x)
#endif

// ---------------- prep kernels ----------------
__global__ void k_cast(const float* __restrict__ s, bf16_t* __restrict__ d, int n4) {
  int i = blockIdx.x * 256 + threadIdx.x;
  if (i >= n4) return;
  float4 v = reinterpret_cast<const float4*>(s)[i];
  union { bf16_t b[4]; unsigned long long u; } pk;
  pk.b[0] = (bf16_t)v.x; pk.b[1] = (bf16_t)v.y;
  pk.b[2] = (bf16_t)v.z; pk.b[3] = (bf16_t)v.w;
  reinterpret_cast<unsigned long long*>(d)[i] = pk.u;
}

__global__ void k_cast_w(const float* __restrict__ w0, const float* __restrict__ w1,
                         const float* __restrict__ w2, const float* __restrict__ w3,
                         bf16_t* __restrict__ dst) {
  int z = blockIdx.y;
  const float* s = (z == 0) ? w0 : (z == 1) ? w1 : (z == 2) ? w2 : w3;
  int i = blockIdx.x * 256 + threadIdx.x;
  float4 v = reinterpret_cast<const float4*>(s)[i];
  union { bf16_t b[4]; unsigned long long u; } pk;
  pk.b[0] = (bf16_t)v.x; pk.b[1] = (bf16_t)v.y;
  pk.b[2] = (bf16_t)v.z; pk.b[3] = (bf16_t)v.w;
  reinterpret_cast<unsigned long long*>(dst + (size_t)z * 1048576)[i] = pk.u;
}

__global__ void k_rope_table(const int* __restrict__ pos, float2* __restrict__ rt) {
  int s = blockIdx.x * 8 + (threadIdx.x >> 5);
  int f = threadIdx.x & 31;
  float p = (float)pos[s];
  float inv = powf(10000.0f, -(float)(2 * f) / 64.0f);
  float a = p * inv;
  rt[s * 32 + f] = make_float2(cosf(a), sinf(a));
}

// ======= R8 GEMM body: BM=256, BN=128, BK=32, 32 K-tiles, 3 LDS slots =======
// Slot (24576B): A 16KB = 16 groups x 1KB; B 8KB at +16384 = 8 groups.
//   1KB group = 16 rows x 32 k, lane-ordered: lane (hi*16+c) holds row c,
//   k in [hi*8,hi*8+8) -> frag read = base + lane*16 (lane-linear, 0-conflict).
// Stage: granule s_ (A: l*512+t, l=0,1; B: s_=t): row=((s_>>6)<<4)|(s_&15),
//   koff=((s_>>4)&3)*8; LDS dst linear t*16 (permutation folded into source).
// Pipeline/races (1 raw barrier per iter):
//   - every ds_read is consumed by an MFMA in the SAME iter (compiler inserts
//     fine lgkmcnt) -> retired before the end-of-iter barrier;
//   - stage(j+2) writes slot (j-1)%3, whose reads retired before barrier(j-1),
//     and the stage is issued after barrier(j-1) -> no WAR;
//   - VMCNT(3) at iter end leaves only tile j+2's 3 loads outstanding ->
//     tile j+1 resident; barrier AFTER vmcnt makes per-wave residency
//     block-wide. Memory ops cannot cross the "memory"-clobber VMCNT asm.
#define GEMM_R8_BODY(Aptr, Bptr)                                               \
  __shared__ alignas(16) char LDSbuf[73728];                                   \
  const int t = threadIdx.x;                                                   \
  const int lane = t & 63, w = t >> 6;                                         \
  const int hi = lane >> 4, c = lane & 15;                                     \
  const int wm4 = w >> 1, wn2 = w & 1;                                         \
  const bf16_t* gA[2];                                                         \
  _Pragma("unroll") for (int l = 0; l < 2; ++l) {                              \
    int s_ = l * 512 + t;                                                      \
    gA[l] = (Aptr) + (size_t)(i0 + ((s_ >> 6) << 4) + (s_ & 15)) * 1024 +      \
            ((s_ >> 4) & 3) * 8;                                               \
  }                                                                            \
  const bf16_t* gB = (Bptr) + (size_t)(e0 + ((t >> 6) << 4) + (t & 15)) * 1024 \
                     + ((t >> 4) & 3) * 8;                                     \
  auto stage = [&](int slot, int kt) {                                         \
    char* d0 = LDSbuf + slot * 24576 + t * 16;                                 \
    gload_lds16(gA[0] + kt * 32, d0);                                          \
    gload_lds16(gA[1] + kt * 32, d0 + 8192);                                   \
    gload_lds16(gB + kt * 32, d0 + 16384);                                     \
  };                                                                           \
  f32x4 acc[4][4] = {};                                                        \
  stage(0, 0); stage(1, 1);                                                    \
  VMCNT(3);                                                                    \
  BAR();                                                                       \
  const char* laB = LDSbuf + wm4 * 4096 + lane * 16;                           \
  const char* lbB = LDSbuf + 16384 + wn2 * 4096 + lane * 16;                   \
  int sl = 0, sls = 2;                                                         \
  for (int j = 0; j < 32; ++j) {                                               \
    if (j < 30) stage(sls, j + 2);                                             \
    const char* la = laB + sl * 24576;                                         \
    const char* lb = lbB + sl * 24576;                                         \
    bf16x8 af[4], bg[4];                                                       \
    _Pragma("unroll") for (int fr = 0; fr < 4; ++fr)                           \
      af[fr] = *(const bf16x8*)(la + fr * 1024);                               \
    _Pragma("unroll") for (int nc = 0; nc < 4; ++nc)                           \
      bg[nc] = *(const bf16x8*)(lb + nc * 1024);                               \
    _Pragma("unroll") for (int fr = 0; fr < 4; ++fr)                           \
      _Pragma("unroll") for (int nc = 0; nc < 4; ++nc)                         \
        acc[fr][nc] = mfma16(af[fr], bg[nc], acc[fr][nc]);                     \
    if (j < 30) { VMCNT(3); } else if (j == 30) { VMCNT0(); }                  \
    BAR();                                                                     \
    sl = (sl == 2) ? 0 : sl + 1;                                               \
    sls = (sls == 2) ? 0 : sls + 1;                                            \
  }

// ---------------- fused QKV GEMM: N=3072 (Wq|Wk|Wv concat) ----------------
// 768 blocks = 32 m (fastest) x 24 n: concurrent blocks share one B-panel
// (256KB, L2-hot per XCD) and stream distinct A tiles (R2's proven order).
__global__ __launch_bounds__(512) void k_gemm_qkv(
    const bf16_t* __restrict__ Xb, const bf16_t* __restrict__ Wqkv,
    const float* __restrict__ bq, const float* __restrict__ bk,
    const float* __restrict__ bv, const float2* __restrict__ rt,
    bf16_t* __restrict__ Qh, bf16_t* __restrict__ Kh, bf16_t* __restrict__ Vt) {
  const int bid = blockIdx.x;
  const int i0 = (bid & 31) * 256;
  const int e0 = (bid >> 5) * 128;

  GEMM_R8_BODY(Xb, Wqkv)

  // Epilogue: one head per wave (64-col window at ez0).
  const int z = e0 >> 10;                       // 0:Q 1:K 2:V
  const int ez0 = (e0 & 1023) + wn2 * 64;       // multiple of 64
  const int h = ez0 >> 6;
  const float* bias = (z == 0) ? bq : (z == 1) ? bk : bv;
  if (z == 2) {
#pragma unroll
    for (int fr = 0; fr < 4; ++fr) {
      int i = i0 + wm4 * 64 + fr * 16 + hi * 4;
      int b_ = i >> 10, s = i & 1023;
#pragma unroll
      for (int nc = 0; nc < 4; ++nc) {
        int dk = nc * 16 + c;
        float bv_ = bias[ez0 + dk];
        union { bf16_t b[4]; unsigned long long u; } pk;
#pragma unroll
        for (int r = 0; r < 4; ++r) pk.b[r] = (bf16_t)(acc[fr][nc][r] + bv_);
        __builtin_memcpy(&Vt[((size_t)((b_ * 16 + h) * 64 + dk)) * 1024 + s], pk.b, 8);
      }
    }
  } else {
    bf16_t* O = (z == 0) ? Qh : Kh;
    // Q folds 1/sqrt(64) * log2(e): attn softmax runs in exp2 domain.
    const float scl = (z == 0) ? 0.18033688011112042f : 1.0f;
#pragma unroll
    for (int fr = 0; fr < 4; ++fr) {
      int i = i0 + wm4 * 64 + fr * 16 + hi * 4;
      int b_ = i >> 10, sbase = i & 1023;
      size_t obase = (size_t)((b_ * 16 + h) * 1024);
#pragma unroll
      for (int nc = 0; nc < 2; ++nc) {          // f<32; partner f+32 = frag nc+2
        int f = nc * 16 + c;
        float b1_ = bias[ez0 + f], b2_ = bias[ez0 + f + 32];
#pragma unroll
        for (int r = 0; r < 4; ++r) {
          int s = sbase + r;
          float2 cs = rt[s * 32 + f];
          float q1 = acc[fr][nc][r] + b1_;
          float q2 = acc[fr][nc + 2][r] + b2_;
          O[(obase + s) * 64 + f] = (bf16_t)((q1 * cs.x - q2 * cs.y) * scl);
          O[(obase + s) * 64 + f + 32] = (bf16_t)((q1 * cs.y + q2 * cs.x) * scl);
        }
      }
    }
  }
}

// ---------------- out projection (same engine): 256 blocks = 32m x 8n ------
__global__ __launch_bounds__(512) void k_gemm_out(
    const bf16_t* __restrict__ Og, const bf16_t* __restrict__ Wob,
    const float* __restrict__ bo, float* __restrict__ out) {
  const int bid = blockIdx.x;
  const int i0 = (bid & 31) * 256;
  const int e0 = (bid >> 5) * 128;

  GEMM_R8_BODY(Og, Wob)

#pragma unroll
  for (int fr = 0; fr < 4; ++fr) {
    int i = i0 + wm4 * 64 + fr * 16 + hi * 4;
#pragma unroll
    for (int nc = 0; nc < 4; ++nc) {
      int e = e0 + wn2 * 64 + nc * 16 + c;
      float bv_ = bo[e];
#pragma unroll
      for (int r = 0; r < 4; ++r)
        out[(size_t)(i + r) * 1024 + e] = acc[fr][nc][r] + bv_;
    }
  }
}

// ---------------- flash attention (R5, verified) ----------------
__global__ __launch_bounds__(512) void k_attn(
    const bf16_t* __restrict__ Qh, const bf16_t* __restrict__ Kh,
    const bf16_t* __restrict__ Vt, bf16_t* __restrict__ Og) {
  __shared__ alignas(16) char KL[3][8192];
  __shared__ alignas(16) char VL[3][8192];
  __shared__ alignas(16) char PL[8][2048];
  const int t = threadIdx.x;
  const int lane = t & 63, w = t >> 6;
  const int hi = lane >> 4, c = lane & 15;
  const int bid = blockIdx.x;
  const int wg = (bid & 7) * 128 + (bid >> 3);
  const int bh = wg >> 3, qt = wg & 7;
  const size_t base = (size_t)bh * 64 * 1024;
  const int q0 = qt * 128 + w * 16;

  const int sc = t & 15, sks = (t >> 4) & 7, sfr = t >> 7;
  const bf16_t* srcK = Kh + base + (size_t)(sfr * 16 + sc) * 64 + sks * 8;
  const bf16_t* srcV = Vt + base + (size_t)(sfr * 16 + sc) * 1024 + sks * 8;
  auto stage = [&](int b3, int kt) {
    gload_lds16(srcK + (size_t)kt * 64 * 64, &KL[b3][0] + t * 16);
    gload_lds16(srcV + kt * 64, &VL[b3][0] + t * 16);
  };

  bf16x8 qf[2];
  qf[0] = *(const bf16x8*)&Qh[base + (size_t)(q0 + c) * 64 + hi * 8];
  qf[1] = *(const bf16x8*)&Qh[base + (size_t)(q0 + c) * 64 + 32 + hi * 8];

  f32x4 o[4] = {};
  float m = -1e30f, lsum = 0.f;

  stage(0, 0);
  stage(1, 1);
  VMCNT(2);
  BAR();

  char* const plw = &PL[w][0];
  for (int kt = 0; kt < 16; ++kt) {
    const int b3 = kt % 3;
    if (kt + 2 < 16) stage((kt + 2) % 3, kt + 2);

    const char* kb = &KL[b3][0] + lane * 16;
    f32x4 st[4] = {};
#pragma unroll
    for (int ni = 0; ni < 4; ++ni)
#pragma unroll
      for (int kk = 0; kk < 2; ++kk)
        st[ni] = mfma16(*(const bf16x8*)(kb + ni * 2048 + kk * 1024), qf[kk], st[ni]);

    float pmax = -1e30f;
#pragma unroll
    for (int ni = 0; ni < 4; ++ni)
#pragma unroll
      for (int r = 0; r < 4; ++r) pmax = fmaxf(pmax, st[ni][r]);
    pmax = fmaxf(pmax, __shfl_xor(pmax, 16));
    pmax = fmaxf(pmax, __shfl_xor(pmax, 32));
    float mn = fmaxf(m, pmax);
    float scale = EXP2F(m - mn);
    m = mn;
    float psum = 0.f;
#pragma unroll
    for (int ni = 0; ni < 4; ++ni) {
      union { bf16_t b[4]; unsigned long long u; } pk;
#pragma unroll
      for (int r = 0; r < 4; ++r) {
        float p = EXP2F(st[ni][r] - mn);
        psum += p;
        pk.b[r] = (bf16_t)p;
      }
      __builtin_memcpy(plw + (ni * 2 + (hi >> 1)) * 256 + c * 16 + (hi & 1) * 8,
                       pk.b, 8);
    }
    psum += __shfl_xor(psum, 16);
    psum += __shfl_xor(psum, 32);
    lsum = lsum * scale + psum;
#pragma unroll
    for (int od = 0; od < 4; ++od)
#pragma unroll
      for (int r = 0; r < 4; ++r) o[od][r] *= scale;

    const char* vb = &VL[b3][0] + lane * 16;
#pragma unroll
    for (int od = 0; od < 4; ++od)
#pragma unroll
      for (int kk = 0; kk < 2; ++kk) {
        bf16x8 vf = *(const bf16x8*)(vb + od * 2048 + kk * 1024);
        bf16x8 pa = *(const bf16x8*)(plw + kk * 1024 + lane * 16);
        o[od] = mfma16(vf, pa, o[od]);
      }

    if (kt < 14) { VMCNT(2); } else if (kt == 14) { VMCNT0(); }
    if (kt < 15) { __builtin_amdgcn_sched_barrier(0); BAR(); __builtin_amdgcn_sched_barrier(0); }
  }

  float invl = 1.0f / lsum;
  int b_ = bh >> 4, h = bh & 15;
  size_t rowoff = ((size_t)(b_ * 1024 + q0 + c)) * 1024 + h * 64;
#pragma unroll
  for (int od = 0; od < 4; ++od) {
    union { bf16_t b[4]; unsigned long long u; } pk;
#pragma unroll
    for (int r = 0; r < 4; ++r) pk.b[r] = (bf16_t)(o[od][r] * invl);
    __builtin_memcpy(&Og[rowoff + od * 16 + hi * 4], pk.b, 8);
  }
}

extern "C" void kernel_launch(void* const* d_in, const int* in_sizes, int n_in,
                              void* d_out, int out_size, void* d_ws, size_t ws_size,
                              hipStream_t stream) {
  const float* x = (const float*)d_in[0];
  const int* pos = (const int*)d_in[1];
  const float* Wq = (const float*)d_in[2];
  const float* bq = (const float*)d_in[3];
  const float* Wk = (const float*)d_in[4];
  const float* bk = (const float*)d_in[5];
  const float* Wv = (const float*)d_in[6];
  const float* bv = (const float*)d_in[7];
  const float* Wo = (const float*)d_in[8];
  const float* bo = (const float*)d_in[9];
  float* out = (float*)d_out;

  // ws: [0,16M) Xb (reused as Og) | [16M,24M) Wqkv(6M)+Wob(2M) contiguous
  //     [24M,40M) Vt | [42M,..) rope table.  Q,K live in d_out (32MB).
  char* ws = (char*)d_ws;
  bf16_t* Xb = (bf16_t*)ws;
  bf16_t* Wqkv = (bf16_t*)(ws + (16u << 20));
  bf16_t* Wob = (bf16_t*)(ws + (22u << 20));
  bf16_t* Vt = (bf16_t*)(ws + (24u << 20));
  float2* rt = (float2*)(ws + (42u << 20));
  bf16_t* Qh = (bf16_t*)d_out;
  bf16_t* Kh = (bf16_t*)d_out + (size_t)8 * 1024 * 1024;
  bf16_t* Og = Xb;

  k_cast<<<8192, 256, 0, stream>>>(x, Xb, 8192 * 1024 / 4);
  k_cast_w<<<dim3(1024, 4), 256, 0, stream>>>(Wq, Wk, Wv, Wo, Wqkv);
  k_rope_table<<<128, 256, 0, stream>>>(pos, rt);

  k_gemm_qkv<<<768, 512, 0, stream>>>(Xb, Wqkv, bq, bk, bv, rt, Qh, Kh, Vt);
  k_attn<<<1024, 512, 0, stream>>>(Qh, Kh, Vt, Og);
  k_gemm_out<<<256, 512, 0, stream>>>(Og, Wob, bo, out);
}